// Round 4
// baseline (3080.776 us; speedup 1.0000x reference)
//
#include <hip/hip_runtime.h>
#include <math.h>

// GPT-2-ish forward: V=50257, C=1024, H=16, L=8, B=2, T=1024, D=64
#define V_ 50257
#define C_ 1024
#define H_ 16
#define L_ 8
#define B_ 2
#define T_ 1024
#define BT_ 2048
#define CC_ (C_*C_)
#define QLD_ 3072   // packed q|k|v row stride (bf16)

typedef unsigned short ushort_t;
using bf16x8 = __attribute__((ext_vector_type(8))) short;
using f32x4  = __attribute__((ext_vector_type(4))) float;

__device__ __forceinline__ ushort_t f2bf(float f){
  union { float f; unsigned u; } a; a.f = f;
  unsigned r = a.u + 0x7fffu + ((a.u >> 16) & 1u);   // RNE
  return (ushort_t)(r >> 16);
}

__device__ __forceinline__ float wave_sum(float v){
  #pragma unroll
  for(int o=32;o>0;o>>=1) v += __shfl_down(v,o,64);
  return v;
}

// ---------------- conversions ----------------
__global__ __launch_bounds__(256) void cvt_blk(const float* __restrict__ s, ushort_t* __restrict__ d,
    long inner4, int nblk, long dstStride4){
  long total = inner4 * nblk;
  for(long i = (long)blockIdx.x*256 + threadIdx.x; i < total; i += (long)gridDim.x*256){
    long blk = i / inner4, r = i - blk*inner4;
    float4 v = ((const float4*)s)[i];
    ushort4 o; o.x=f2bf(v.x); o.y=f2bf(v.y); o.z=f2bf(v.z); o.w=f2bf(v.w);
    ((ushort4*)d)[blk*dstStride4 + r] = o;
  }
}

__global__ __launch_bounds__(256) void pack_qkv_bias(const float* __restrict__ bq,
    const float* __restrict__ bk, const float* __restrict__ bv, float* __restrict__ dst){
  int i = blockIdx.x*256 + threadIdx.x;          // L*3072
  int l = i / QLD_, c = i - l*QLD_;
  float v;
  if(c < C_)            v = bq[l*C_ + c];
  else if(c < 2*C_)     v = bk[l*C_ + c - C_];
  else                  v = bv[l*C_ + c - 2*C_];
  dst[i] = v;
}

__global__ __launch_bounds__(256) void embed_kernel(const int* __restrict__ idx,
    const float* __restrict__ tok, const float* __restrict__ pos, float* __restrict__ x){
  int i = blockIdx.x*256 + threadIdx.x;
  int c = i & (C_-1); int bt = i >> 10; int t = bt & (T_-1);
  x[i] = tok[(size_t)idx[bt]*C_ + c] + pos[t*C_ + c];
}

// LayerNorm over C=1024; writes f32 (outF) or bf16 (outB). in==outF safe.
__global__ __launch_bounds__(256) void ln_kernel(const float* in, const float* __restrict__ w,
    const float* __restrict__ b, float* outF, ushort_t* outB){
  int row = blockIdx.x;
  const float* xr = in + (size_t)row*C_;
  float vals[4]; float sum=0.f, sq=0.f;
  #pragma unroll
  for(int l=0;l<4;l++){ float v = xr[threadIdx.x + l*256]; vals[l]=v; sum+=v; sq+=v*v; }
  __shared__ float r1[4], r2[4];
  float s1 = wave_sum(sum), s2 = wave_sum(sq);
  int wid = threadIdx.x>>6, lane = threadIdx.x&63;
  if(lane==0){ r1[wid]=s1; r2[wid]=s2; }
  __syncthreads();
  float tot  = r1[0]+r1[1]+r1[2]+r1[3];
  float tot2 = r2[0]+r2[1]+r2[2]+r2[3];
  float mu  = tot * (1.f/C_);
  float var = tot2 * (1.f/C_) - mu*mu;
  float inv = rsqrtf(var + 1e-5f);
  #pragma unroll
  for(int l=0;l<4;l++){
    int c = threadIdx.x + l*256;
    float v = (vals[l]-mu)*inv*w[c] + b[c];
    if(outB) outB[(size_t)row*C_ + c] = f2bf(v);
    else     outF[(size_t)row*C_ + c] = v;
  }
}

// ---------------- bf16 MFMA GEMM ----------------
// grid: (x = M/128, y = N/BN)  -- M-fastest for weight-panel L2/L3 reuse.
// nt=1: nontemporal f32 stores (head logits -- keep W L3-resident).
template<int BN>
__global__ __launch_bounds__(256) void gemm_mfma(
    const ushort_t* __restrict__ A, const ushort_t* __restrict__ W,
    const float* __restrict__ bias, const float* resid,
    float* outF, ushort_t* outB,
    int M, int N, int K, int act, int nt)
{
  constexpr int BM = 128;
  constexpr int NSB = BN/16;          // B-subtiles (4/8/16)
  constexpr int NBF = BN/32;          // B frags per wave (2/4/8)
  __shared__ __align__(16) short sA[2][8*512];
  __shared__ __align__(16) short sB[2][NSB*512];
  const int tid  = threadIdx.x;
  const int lane = tid & 63, wid = tid >> 6;
  const int wr = wid >> 1, wc = wid & 1;
  const int m0 = blockIdx.x * BM, n0 = blockIdx.y * BN;
  const int r16 = lane & 15, kq = lane >> 4;

  auto stage = [&](int buf, int k0){
    #pragma unroll
    for(int s2=0; s2<2; ++s2){                  // A: 2 subtiles per wave
      int s = wid*2 + s2;
      const ushort_t* g = A + (size_t)(m0 + s*16 + r16)*K + k0 + kq*8;
      __builtin_amdgcn_global_load_lds((const __attribute__((address_space(1))) void*)g,
          (__attribute__((address_space(3))) void*)&sA[buf][s*512], 16, 0, 0);
    }
    #pragma unroll
    for(int s2=0; s2<NSB/4; ++s2){              // B: NSB/4 subtiles per wave
      int s = wid*(NSB/4) + s2;
      int gn = n0 + s*16 + r16; if(gn >= N) gn = N-1;   // head tail clamp
      const ushort_t* g = W + (size_t)gn*K + k0 + kq*8;
      __builtin_amdgcn_global_load_lds((const __attribute__((address_space(1))) void*)g,
          (__attribute__((address_space(3))) void*)&sB[buf][s*512], 16, 0, 0);
    }
  };

  f32x4 acc[4][NBF];
  #pragma unroll
  for(int i=0;i<4;i++)
    #pragma unroll
    for(int j=0;j<NBF;j++) acc[i][j] = (f32x4){0.f,0.f,0.f,0.f};

  const int NT = K >> 5;
  stage(0, 0);
  int cur = 0;
  for(int t=0; t<NT; ++t){
    __syncthreads();
    if(t+1 < NT) stage(cur^1, (t+1)*32);
    bf16x8 af[4], bfr[NBF];
    #pragma unroll
    for(int m=0;m<4;m++) af[m] = *(const bf16x8*)&sA[cur][(wr*4+m)*512 + lane*8];
    #pragma unroll
    for(int n=0;n<NBF;n++) bfr[n] = *(const bf16x8*)&sB[cur][(wc*NBF+n)*512 + lane*8];
    __builtin_amdgcn_s_setprio(1);
    #pragma unroll
    for(int m=0;m<4;m++)
      #pragma unroll
      for(int n=0;n<NBF;n++)
        acc[m][n] = __builtin_amdgcn_mfma_f32_16x16x32_bf16(af[m], bfr[n], acc[m][n], 0, 0, 0);
    __builtin_amdgcn_s_setprio(0);
    cur ^= 1;
  }

  // C/D layout: col = lane&15, row = (lane>>4)*4 + reg
  const int colb = n0 + wc*(BN/2);
  #pragma unroll
  for(int m=0;m<4;m++){
    int rowb = m0 + wr*64 + m*16 + kq*4;
    #pragma unroll
    for(int n=0;n<NBF;n++){
      int col = colb + n*16 + r16;
      if(col >= N) continue;
      float bv = bias ? bias[col] : 0.f;
      #pragma unroll
      for(int i=0;i<4;i++){
        int row = rowb + i;
        float v = acc[m][n][i] + bv;
        if(act) v = 0.5f*v*(1.f + erff(v*0.70710678118654752f));
        if(resid) v += resid[(size_t)row*N + col];
        if(outB) outB[(size_t)row*N + col] = f2bf(v);
        else if(nt) __builtin_nontemporal_store(v, &outF[(size_t)row*N + col]);
        else outF[(size_t)row*N + col] = v;
      }
    }
  }
}

// ---------------- fused flash attention (bf16 MFMA, KVBLK=64) ----------------
// Block: 64 q rows (4 waves x 16). Swapped QK^T (S^T = K.Q^T): softmax over k is
// lane-local 16 vals + 2 shfl_xor. K staged fragment-ordered via global_load_lds;
// V transposed via per-lane writes (stride-68 rows: 2-way-free banks). Causal.
__global__ __launch_bounds__(256) void flash_kernel(const ushort_t* __restrict__ qkv,
    ushort_t* __restrict__ y){
  const int tid = threadIdx.x, lane = tid & 63, wid = tid >> 6;
  const int r16 = lane & 15, kq = lane >> 4;
  const int qt = blockIdx.x, bh = blockIdx.y, b = bh >> 4, h = bh & 15;
  const int q0 = qt*64, qw0 = q0 + wid*16;
  const int qa = qw0 + r16;

  __shared__ __align__(16) short Kt[8][512];     // 8 K-subtiles (kr 0..3, d-half 0..1)
  __shared__ __align__(16) short VT[64][68];     // V^T [d][k]
  __shared__ __align__(16) short Pl[4][16][68];  // per-wave P [q][k]
  __shared__ __align__(16) short Ol[4][16][68];  // per-wave O staging [q][d]

  const size_t rowQ = (size_t)(b*T_ + qa)*QLD_ + h*64 + kq*8;
  bf16x8 qf0 = *(const bf16x8*)(qkv + rowQ);       // d 0..31 slice
  bf16x8 qf1 = *(const bf16x8*)(qkv + rowQ + 32);  // d 32..63

  f32x4 acc[4];
  #pragma unroll
  for(int t=0;t<4;t++) acc[t] = (f32x4){0.f,0.f,0.f,0.f};
  float m_r = -INFINITY, l_r = 0.f;

  const int njt = qt + 1;
  for(int jt=0; jt<njt; ++jt){
    __syncthreads();   // all waves done reading previous K/VT
    #pragma unroll
    for(int s2=0;s2<2;s2++){   // stage K subtiles 2w, 2w+1
      int s = wid*2 + s2;
      const ushort_t* g = qkv + (size_t)(b*T_ + jt*64 + (s>>1)*16 + r16)*QLD_
                          + C_ + h*64 + (s&1)*32 + kq*8;
      __builtin_amdgcn_global_load_lds((const __attribute__((address_space(1))) void*)g,
          (__attribute__((address_space(3))) void*)&Kt[s][lane*8], 16, 0, 0);
    }
    #pragma unroll
    for(int a2=0;a2<2;a2++){   // stage V^T: wave covers d-slice (a2*4+wid)*8, all 64 k
      int d0 = (a2*4 + wid)*8;
      bf16x8 vv = *(const bf16x8*)(qkv + (size_t)(b*T_ + jt*64 + lane)*QLD_ + 2*C_ + h*64 + d0);
      #pragma unroll
      for(int j=0;j<8;j++) VT[d0+j][lane] = vv[j];
    }
    __syncthreads();   // staging visible (barrier drains vmcnt+lgkm)

    // S^T: 4 tiles of 16k x 16q
    f32x4 st[4];
    __builtin_amdgcn_s_setprio(1);
    #pragma unroll
    for(int kr=0;kr<4;kr++){
      st[kr] = (f32x4){0.f,0.f,0.f,0.f};
      st[kr] = __builtin_amdgcn_mfma_f32_16x16x32_bf16(*(const bf16x8*)&Kt[kr*2+0][lane*8], qf0, st[kr], 0,0,0);
      st[kr] = __builtin_amdgcn_mfma_f32_16x16x32_bf16(*(const bf16x8*)&Kt[kr*2+1][lane*8], qf1, st[kr], 0,0,0);
    }
    __builtin_amdgcn_s_setprio(0);

    float vals[16]; float mx = m_r;
    if(jt == njt-1){           // diagonal tile: mask
      #pragma unroll
      for(int kr=0;kr<4;kr++)
        #pragma unroll
        for(int i=0;i<4;i++){
          int ka = jt*64 + kr*16 + 4*kq + i;
          float v = (ka <= qa) ? st[kr][i]*0.125f : -INFINITY;
          vals[kr*4+i] = v; mx = fmaxf(mx, v);
        }
    } else {                   // fully below diagonal
      #pragma unroll
      for(int kr=0;kr<4;kr++)
        #pragma unroll
        for(int i=0;i<4;i++){
          float v = st[kr][i]*0.125f;
          vals[kr*4+i] = v; mx = fmaxf(mx, v);
        }
    }
    mx = fmaxf(mx, __shfl_xor(mx, 16, 64));
    mx = fmaxf(mx, __shfl_xor(mx, 32, 64));     // mx finite (>=1 unmasked k per q row)
    float alpha = __expf(m_r - mx);
    float ps = 0.f;
    #pragma unroll
    for(int kr=0;kr<4;kr++){
      float p0 = __expf(vals[kr*4+0]-mx), p1 = __expf(vals[kr*4+1]-mx);
      float p2 = __expf(vals[kr*4+2]-mx), p3 = __expf(vals[kr*4+3]-mx);
      ps += (p0+p1)+(p2+p3);
      unsigned u0 = (unsigned)f2bf(p0) | ((unsigned)f2bf(p1)<<16);
      unsigned u1 = (unsigned)f2bf(p2) | ((unsigned)f2bf(p3)<<16);
      *(unsigned*)&Pl[wid][r16][kr*16 + 4*kq]     = u0;
      *(unsigned*)&Pl[wid][r16][kr*16 + 4*kq + 2] = u1;
    }
    ps += __shfl_xor(ps, 16, 64);
    ps += __shfl_xor(ps, 32, 64);
    l_r = l_r*alpha + ps; m_r = mx;
    #pragma unroll
    for(int t=0;t<4;t++)
      #pragma unroll
      for(int j=0;j<4;j++) acc[t][j] *= alpha;

    // PV: O^T[d][q] += V^T(16d x 32k) . P^T(32k x 16q), 4 d-tiles x 2 k-halves
    union { bf16x8 v8; uint2 u2[2]; } pf, vf;
    __builtin_amdgcn_s_setprio(1);
    #pragma unroll
    for(int ks2=0; ks2<2; ks2++){
      pf.u2[0] = *(const uint2*)&Pl[wid][r16][ks2*32 + kq*8];
      pf.u2[1] = *(const uint2*)&Pl[wid][r16][ks2*32 + kq*8 + 4];
      #pragma unroll
      for(int db=0; db<4; db++){
        vf.u2[0] = *(const uint2*)&VT[16*db + r16][ks2*32 + kq*8];
        vf.u2[1] = *(const uint2*)&VT[16*db + r16][ks2*32 + kq*8 + 4];
        acc[db] = __builtin_amdgcn_mfma_f32_16x16x32_bf16(vf.v8, pf.v8, acc[db], 0,0,0);
      }
    }
    __builtin_amdgcn_s_setprio(0);
  }

  // epilogue: normalize, transpose via LDS, coalesced bf16 store
  float linv = 1.f / l_r;
  #pragma unroll
  for(int db=0; db<4; db++)
    #pragma unroll
    for(int i=0;i<4;i++)
      Ol[wid][r16][16*db + 4*kq + i] = (short)f2bf(acc[db][i]*linv);
  int q = lane >> 2, c0 = (lane & 3)*16;
  const short* src = &Ol[wid][q][c0];
  uint2 a0 = *(const uint2*)(src+0), a1 = *(const uint2*)(src+4);
  uint2 a2 = *(const uint2*)(src+8), a3 = *(const uint2*)(src+12);
  ushort_t* dst = y + (size_t)(b*T_ + qw0 + q)*C_ + h*64 + c0;
  uint4 w0 = {a0.x, a0.y, a1.x, a1.y}, w1 = {a2.x, a2.y, a3.x, a3.y};
  *(uint4*)(dst+0) = w0;
  *(uint4*)(dst+8) = w1;
}

// ---------------- f32 GEMM fallback (head only, if ws too small) ----------------
__global__ __launch_bounds__(256) void gemm_nt(const float* __restrict__ A, const float* __restrict__ W,
    const float* __restrict__ bias, const float* resid, float* Cm,
    int M, int N, int K, int act){
  __shared__ float As[16][68];
  __shared__ float Bs[16][68];
  int m0 = blockIdx.y*64, n0 = blockIdx.x*64;
  int tid = threadIdx.x;
  int tx = tid & 15, ty = tid >> 4;
  float acc[4][4] = {};
  for(int k0=0;k0<K;k0+=16){
    #pragma unroll
    for(int l=0;l<4;l++){
      int li = tid + l*256;
      int r = li >> 4, c = li & 15;
      int gm = m0 + r, gn = n0 + r, gk = k0 + c;
      As[c][r] = (gm<M) ? A[(size_t)gm*K + gk] : 0.f;
      Bs[c][r] = (gn<N) ? W[(size_t)gn*K + gk] : 0.f;
    }
    __syncthreads();
    #pragma unroll
    for(int k=0;k<16;k++){
      float4 av = *(const float4*)&As[k][ty*4];
      float4 bv = *(const float4*)&Bs[k][tx*4];
      float a[4] = {av.x, av.y, av.z, av.w};
      float b4[4] = {bv.x, bv.y, bv.z, bv.w};
      #pragma unroll
      for(int i=0;i<4;i++)
        #pragma unroll
        for(int j=0;j<4;j++)
          acc[i][j] = fmaf(a[i], b4[j], acc[i][j]);
    }
    __syncthreads();
  }
  #pragma unroll
  for(int i=0;i<4;i++){
    int m = m0 + ty*4 + i; if(m>=M) continue;
    #pragma unroll
    for(int j=0;j<4;j++){
      int n = n0 + tx*4 + j; if(n>=N) continue;
      float v = acc[i][j];
      if(bias) v += bias[n];
      if(act)  v = 0.5f*v*(1.f + erff(v*0.70710678118654752f));
      if(resid) v += resid[(size_t)m*N + n];
      Cm[(size_t)m*N + n] = v;
    }
  }
}

extern "C" void kernel_launch(void* const* d_in, const int* in_sizes, int n_in,
                              void* d_out, int out_size, void* d_ws, size_t ws_size,
                              hipStream_t stream) {
  const int*   idx  = (const int*)  d_in[0];
  const float* tok  = (const float*)d_in[1];
  const float* pos  = (const float*)d_in[2];
  const float* Wq   = (const float*)d_in[3];
  const float* bq   = (const float*)d_in[4];
  const float* Wk   = (const float*)d_in[5];
  const float* bk   = (const float*)d_in[6];
  const float* Wv   = (const float*)d_in[7];
  const float* bv   = (const float*)d_in[8];
  const float* Wp   = (const float*)d_in[9];
  const float* bp   = (const float*)d_in[10];
  const float* ln1w = (const float*)d_in[11];
  const float* ln1b = (const float*)d_in[12];
  const float* ln2w = (const float*)d_in[13];
  const float* ln2b = (const float*)d_in[14];
  const float* W1   = (const float*)d_in[15];
  const float* b1   = (const float*)d_in[16];
  const float* W2   = (const float*)d_in[17];
  const float* b2   = (const float*)d_in[18];
  const float* lnfw = (const float*)d_in[19];
  const float* lnfb = (const float*)d_in[20];
  const float* headw= (const float*)d_in[21];

  float* out = (float*)d_out;
  ushort_t* qkvb = (ushort_t*)(out);                  //  6,291,456 bf16
  ushort_t* hb   = (ushort_t*)(out + 3145728);        //  2,097,152 bf16
  ushort_t* yb   = (ushort_t*)(out + 4194304);        //  2,097,152 bf16
  ushort_t* mb   = (ushort_t*)(out + 5242880);        //  8,388,608 bf16
  ushort_t* wqkv = (ushort_t*)(out + 9437184);        // 25,165,824 bf16
  ushort_t* wpb  = (ushort_t*)(out + 22020096);       //  8,388,608 bf16
  ushort_t* w1b  = (ushort_t*)(out + 26214400);       // 33,554,432 bf16
  ushort_t* w2b  = (ushort_t*)(out + 42991616);       // 33,554,432 bf16
  float*    bqkv = out + 59768832;                    //     24,576 f
  float*    x    = (float*)d_ws;
  ushort_t* xb   = (ushort_t*)((float*)d_ws + 2097152);
  ushort_t* whb  = (ushort_t*)((float*)d_ws + 3145728);
  const bool big = ws_size >= (size_t)28877312 * 4;

  cvt_blk<<<2048,256,0,stream>>>(Wq, wqkv,          CC_/4, L_, 3*CC_/4);
  cvt_blk<<<2048,256,0,stream>>>(Wk, wqkv + CC_,    CC_/4, L_, 3*CC_/4);
  cvt_blk<<<2048,256,0,stream>>>(Wv, wqkv + 2*CC_,  CC_/4, L_, 3*CC_/4);
  cvt_blk<<<2048,256,0,stream>>>(Wp, wpb,  (long)L_*CC_/4,   1, (long)L_*CC_/4);
  cvt_blk<<<2048,256,0,stream>>>(W1, w1b,  (long)L_*CC_,     1, (long)L_*CC_);
  cvt_blk<<<2048,256,0,stream>>>(W2, w2b,  (long)L_*CC_,     1, (long)L_*CC_);
  if(big) cvt_blk<<<2048,256,0,stream>>>(headw, whb, (long)V_*C_/4, 1, (long)V_*C_/4);
  pack_qkv_bias<<<L_*QLD_/256,256,0,stream>>>(bq, bk, bv, bqkv);

  embed_kernel<<<BT_*C_/256, 256, 0, stream>>>(idx, tok, pos, x);

  for(int l=0;l<L_;l++){
    ln_kernel<<<BT_,256,0,stream>>>(x, ln1w + l*C_, ln1b + l*C_, nullptr, hb);
    gemm_mfma<128><<<dim3(BT_/128, QLD_/128),256,0,stream>>>(hb, wqkv + (size_t)l*3*CC_,
        bqkv + l*QLD_, nullptr, nullptr, qkvb, BT_, QLD_, C_, 0, 0);
    flash_kernel<<<dim3(T_/64, B_*H_),256,0,stream>>>(qkvb, yb);
    gemm_mfma<64><<<dim3(BT_/128, C_/64),256,0,stream>>>(yb, wpb + (size_t)l*CC_,
        bp + l*C_, x, x, nullptr, BT_, C_, C_, 0, 0);
    ln_kernel<<<BT_,256,0,stream>>>(x, ln2w + l*C_, ln2b + l*C_, nullptr, hb);
    gemm_mfma<128><<<dim3(BT_/128, 4*C_/128),256,0,stream>>>(hb, w1b + (size_t)l*4*CC_,
        b1 + (size_t)l*4*C_, nullptr, nullptr, mb, BT_, 4*C_, C_, 1, 0);
    gemm_mfma<64><<<dim3(BT_/128, C_/64),256,0,stream>>>(mb, w2b + (size_t)l*4*CC_,
        b2 + l*C_, x, x, nullptr, BT_, C_, 4*C_, 0, 0);
  }

  if(big){
    ln_kernel<<<BT_,256,0,stream>>>(x, lnfw, lnfb, nullptr, xb);
    gemm_mfma<256><<<dim3(BT_/128, (V_+255)/256),256,0,stream>>>(xb, whb,
        nullptr, nullptr, out, nullptr, BT_, V_, C_, 0, 1);
  } else {
    ln_kernel<<<BT_,256,0,stream>>>(x, lnfw, lnfb, x, nullptr);
    gemm_nt<<<dim3((V_+63)/64, BT_/64),256,0,stream>>>(x, headw, nullptr, nullptr, out,
                                                       BT_, V_, C_, 0);
  }
}

// Round 5
// 2869.910 us; speedup vs baseline: 1.0735x; 1.0735x over previous
//
#include <hip/hip_runtime.h>
#include <math.h>

// GPT-2-ish forward: V=50257, C=1024, H=16, L=8, B=2, T=1024, D=64
#define V_ 50257
#define C_ 1024
#define H_ 16
#define L_ 8
#define B_ 2
#define T_ 1024
#define BT_ 2048
#define CC_ (C_*C_)
#define QLD_ 3072   // packed q|k|v row stride (bf16)

typedef unsigned short ushort_t;
using bf16x8 = __attribute__((ext_vector_type(8))) short;
using f32x4  = __attribute__((ext_vector_type(4))) float;

__device__ __forceinline__ ushort_t f2bf(float f){
  union { float f; unsigned u; } a; a.f = f;
  unsigned r = a.u + 0x7fffu + ((a.u >> 16) & 1u);   // RNE
  return (ushort_t)(r >> 16);
}

__device__ __forceinline__ float wave_sum(float v){
  #pragma unroll
  for(int o=32;o>0;o>>=1) v += __shfl_down(v,o,64);
  return v;
}

// ---------------- conversions ----------------
__global__ __launch_bounds__(256) void cvt_blk(const float* __restrict__ s, ushort_t* __restrict__ d,
    long inner4, int nblk, long dstStride4){
  long total = inner4 * nblk;
  for(long i = (long)blockIdx.x*256 + threadIdx.x; i < total; i += (long)gridDim.x*256){
    long blk = i / inner4, r = i - blk*inner4;
    float4 v = ((const float4*)s)[i];
    ushort4 o; o.x=f2bf(v.x); o.y=f2bf(v.y); o.z=f2bf(v.z); o.w=f2bf(v.w);
    ((ushort4*)d)[blk*dstStride4 + r] = o;
  }
}

__global__ __launch_bounds__(256) void pack_qkv_bias(const float* __restrict__ bq,
    const float* __restrict__ bk, const float* __restrict__ bv, float* __restrict__ dst){
  int i = blockIdx.x*256 + threadIdx.x;          // L*3072
  int l = i / QLD_, c = i - l*QLD_;
  float v;
  if(c < C_)            v = bq[l*C_ + c];
  else if(c < 2*C_)     v = bk[l*C_ + c - C_];
  else                  v = bv[l*C_ + c - 2*C_];
  dst[i] = v;
}

__global__ __launch_bounds__(256) void embed_kernel(const int* __restrict__ idx,
    const float* __restrict__ tok, const float* __restrict__ pos, float* __restrict__ x){
  int i = blockIdx.x*256 + threadIdx.x;
  int c = i & (C_-1); int bt = i >> 10; int t = bt & (T_-1);
  x[i] = tok[(size_t)idx[bt]*C_ + c] + pos[t*C_ + c];
}

// LayerNorm over C=1024; writes f32 (outF) or bf16 (outB). in==outF safe.
__global__ __launch_bounds__(256) void ln_kernel(const float* in, const float* __restrict__ w,
    const float* __restrict__ b, float* outF, ushort_t* outB){
  int row = blockIdx.x;
  const float* xr = in + (size_t)row*C_;
  float vals[4]; float sum=0.f, sq=0.f;
  #pragma unroll
  for(int l=0;l<4;l++){ float v = xr[threadIdx.x + l*256]; vals[l]=v; sum+=v; sq+=v*v; }
  __shared__ float r1[4], r2[4];
  float s1 = wave_sum(sum), s2 = wave_sum(sq);
  int wid = threadIdx.x>>6, lane = threadIdx.x&63;
  if(lane==0){ r1[wid]=s1; r2[wid]=s2; }
  __syncthreads();
  float tot  = r1[0]+r1[1]+r1[2]+r1[3];
  float tot2 = r2[0]+r2[1]+r2[2]+r2[3];
  float mu  = tot * (1.f/C_);
  float var = tot2 * (1.f/C_) - mu*mu;
  float inv = rsqrtf(var + 1e-5f);
  #pragma unroll
  for(int l=0;l<4;l++){
    int c = threadIdx.x + l*256;
    float v = (vals[l]-mu)*inv*w[c] + b[c];
    if(outB) outB[(size_t)row*C_ + c] = f2bf(v);
    else     outF[(size_t)row*C_ + c] = v;
  }
}

// ---------------- bf16 MFMA GEMM ----------------
// Logical grid: (x = M/128, y = N/BN), M-fastest. XCD-bijective swizzle (T1):
// nwg always divisible by 8 here; puts all M-blocks sharing a W-panel on one
// XCD consecutively -> panel stays in that XCD's L2.
// nt=1: nontemporal f32 stores (head logits -- keep W L3-resident).
template<int BN>
__global__ __launch_bounds__(256) void gemm_mfma(
    const ushort_t* __restrict__ A, const ushort_t* __restrict__ W,
    const float* __restrict__ bias, const float* resid,
    float* outF, ushort_t* outB,
    int M, int N, int K, int act, int nt)
{
  constexpr int BM = 128;
  constexpr int NSB = BN/16;          // B-subtiles (4 or 8)
  constexpr int NBF = BN/32;          // B frags per wave (2 or 4)
  __shared__ __align__(16) short sA[2][8*512];
  __shared__ __align__(16) short sB[2][NSB*512];
  const int tid  = threadIdx.x;
  const int lane = tid & 63, wid = tid >> 6;
  const int wr = wid >> 1, wc = wid & 1;
  // XCD swizzle (bijective: nwg % 8 == 0 for all our launches)
  const int nwg = gridDim.x * gridDim.y;
  const int lid = blockIdx.x + gridDim.x * blockIdx.y;
  const int swz = (lid & 7) * (nwg >> 3) + (lid >> 3);
  const int m0 = (swz % gridDim.x) * BM, n0 = (swz / gridDim.x) * BN;
  const int r16 = lane & 15, kq = lane >> 4;

  auto stage = [&](int buf, int k0){
    #pragma unroll
    for(int s2=0; s2<2; ++s2){                  // A: 2 subtiles per wave
      int s = wid*2 + s2;
      const ushort_t* g = A + (size_t)(m0 + s*16 + r16)*K + k0 + kq*8;
      __builtin_amdgcn_global_load_lds((const __attribute__((address_space(1))) void*)g,
          (__attribute__((address_space(3))) void*)&sA[buf][s*512], 16, 0, 0);
    }
    #pragma unroll
    for(int s2=0; s2<NSB/4; ++s2){              // B: NSB/4 subtiles per wave
      int s = wid*(NSB/4) + s2;
      int gn = n0 + s*16 + r16; if(gn >= N) gn = N-1;   // head tail clamp
      const ushort_t* g = W + (size_t)gn*K + k0 + kq*8;
      __builtin_amdgcn_global_load_lds((const __attribute__((address_space(1))) void*)g,
          (__attribute__((address_space(3))) void*)&sB[buf][s*512], 16, 0, 0);
    }
  };

  f32x4 acc[4][NBF];
  #pragma unroll
  for(int i=0;i<4;i++)
    #pragma unroll
    for(int j=0;j<NBF;j++) acc[i][j] = (f32x4){0.f,0.f,0.f,0.f};

  const int NT = K >> 5;
  stage(0, 0);
  int cur = 0;
  for(int t=0; t<NT; ++t){
    __syncthreads();
    if(t+1 < NT) stage(cur^1, (t+1)*32);
    bf16x8 af[4], bfr[NBF];
    #pragma unroll
    for(int m=0;m<4;m++) af[m] = *(const bf16x8*)&sA[cur][(wr*4+m)*512 + lane*8];
    #pragma unroll
    for(int n=0;n<NBF;n++) bfr[n] = *(const bf16x8*)&sB[cur][(wc*NBF+n)*512 + lane*8];
    #pragma unroll
    for(int m=0;m<4;m++)
      #pragma unroll
      for(int n=0;n<NBF;n++)
        acc[m][n] = __builtin_amdgcn_mfma_f32_16x16x32_bf16(af[m], bfr[n], acc[m][n], 0, 0, 0);
    cur ^= 1;
  }

  // C/D layout: col = lane&15, row = (lane>>4)*4 + reg
  const int colb = n0 + wc*(BN/2);
  #pragma unroll
  for(int m=0;m<4;m++){
    int rowb = m0 + wr*64 + m*16 + kq*4;
    #pragma unroll
    for(int n=0;n<NBF;n++){
      int col = colb + n*16 + r16;
      if(col >= N) continue;
      float bv = bias ? bias[col] : 0.f;
      #pragma unroll
      for(int i=0;i<4;i++){
        int row = rowb + i;
        float v = acc[m][n][i] + bv;
        if(act) v = 0.5f*v*(1.f + erff(v*0.70710678118654752f));
        if(resid) v += resid[(size_t)row*N + col];
        if(outB) outB[(size_t)row*N + col] = f2bf(v);
        else if(nt) __builtin_nontemporal_store(v, &outF[(size_t)row*N + col]);
        else outF[(size_t)row*N + col] = v;
      }
    }
  }
}

// ---------------- fused flash attention (bf16 MFMA, KVBLK=64) ----------------
// Block: 64 q rows (4 waves x 16). Swapped QK^T (S^T = K.Q^T): softmax over k is
// lane-local 16 vals + 2 shfl_xor. XCD swizzle keeps one (b,h)'s q-blocks
// (sharing 256KB K/V) on one XCD. Causal.
__global__ __launch_bounds__(256) void flash_kernel(const ushort_t* __restrict__ qkv,
    ushort_t* __restrict__ y){
  const int tid = threadIdx.x, lane = tid & 63, wid = tid >> 6;
  const int r16 = lane & 15, kq = lane >> 4;
  // grid is (16, 32) = 512 blocks; swizzle bijective (512 % 8 == 0)
  const int lid = blockIdx.x + 16*blockIdx.y;
  const int swz = (lid & 7)*64 + (lid >> 3);
  const int qt = swz & 15, bh = swz >> 4;
  const int b = bh >> 4, h = bh & 15;
  const int q0 = qt*64, qw0 = q0 + wid*16;
  const int qa = qw0 + r16;

  __shared__ __align__(16) short Kt[8][512];     // 8 K-subtiles (kr 0..3, d-half 0..1)
  __shared__ __align__(16) short VT[64][68];     // V^T [d][k]
  __shared__ __align__(16) short Pl[4][16][68];  // per-wave P [q][k]
  __shared__ __align__(16) short Ol[4][16][68];  // per-wave O staging [q][d]

  const size_t rowQ = (size_t)(b*T_ + qa)*QLD_ + h*64 + kq*8;
  bf16x8 qf0 = *(const bf16x8*)(qkv + rowQ);       // d 0..31 slice
  bf16x8 qf1 = *(const bf16x8*)(qkv + rowQ + 32);  // d 32..63

  f32x4 acc[4];
  #pragma unroll
  for(int t=0;t<4;t++) acc[t] = (f32x4){0.f,0.f,0.f,0.f};
  float m_r = -INFINITY, l_r = 0.f;

  const int njt = qt + 1;
  for(int jt=0; jt<njt; ++jt){
    __syncthreads();   // all waves done reading previous K/VT
    #pragma unroll
    for(int s2=0;s2<2;s2++){   // stage K subtiles 2w, 2w+1
      int s = wid*2 + s2;
      const ushort_t* g = qkv + (size_t)(b*T_ + jt*64 + (s>>1)*16 + r16)*QLD_
                          + C_ + h*64 + (s&1)*32 + kq*8;
      __builtin_amdgcn_global_load_lds((const __attribute__((address_space(1))) void*)g,
          (__attribute__((address_space(3))) void*)&Kt[s][lane*8], 16, 0, 0);
    }
    #pragma unroll
    for(int a2=0;a2<2;a2++){   // stage V^T: wave covers d-slice (a2*4+wid)*8, all 64 k
      int d0 = (a2*4 + wid)*8;
      bf16x8 vv = *(const bf16x8*)(qkv + (size_t)(b*T_ + jt*64 + lane)*QLD_ + 2*C_ + h*64 + d0);
      #pragma unroll
      for(int j=0;j<8;j++) VT[d0+j][lane] = vv[j];
    }
    __syncthreads();   // staging visible (barrier drains vmcnt+lgkm)

    // S^T: 4 tiles of 16k x 16q
    f32x4 st[4];
    __builtin_amdgcn_s_setprio(1);
    #pragma unroll
    for(int kr=0;kr<4;kr++){
      st[kr] = (f32x4){0.f,0.f,0.f,0.f};
      st[kr] = __builtin_amdgcn_mfma_f32_16x16x32_bf16(*(const bf16x8*)&Kt[kr*2+0][lane*8], qf0, st[kr], 0,0,0);
      st[kr] = __builtin_amdgcn_mfma_f32_16x16x32_bf16(*(const bf16x8*)&Kt[kr*2+1][lane*8], qf1, st[kr], 0,0,0);
    }
    __builtin_amdgcn_s_setprio(0);

    float vals[16]; float mx = m_r;
    if(jt == njt-1){           // diagonal tile: mask
      #pragma unroll
      for(int kr=0;kr<4;kr++)
        #pragma unroll
        for(int i=0;i<4;i++){
          int ka = jt*64 + kr*16 + 4*kq + i;
          float v = (ka <= qa) ? st[kr][i]*0.125f : -INFINITY;
          vals[kr*4+i] = v; mx = fmaxf(mx, v);
        }
    } else {                   // fully below diagonal
      #pragma unroll
      for(int kr=0;kr<4;kr++)
        #pragma unroll
        for(int i=0;i<4;i++){
          float v = st[kr][i]*0.125f;
          vals[kr*4+i] = v; mx = fmaxf(mx, v);
        }
    }
    mx = fmaxf(mx, __shfl_xor(mx, 16, 64));
    mx = fmaxf(mx, __shfl_xor(mx, 32, 64));     // mx finite (>=1 unmasked k per q row)
    float alpha = __expf(m_r - mx);
    float ps = 0.f;
    #pragma unroll
    for(int kr=0;kr<4;kr++){
      float p0 = __expf(vals[kr*4+0]-mx), p1 = __expf(vals[kr*4+1]-mx);
      float p2 = __expf(vals[kr*4+2]-mx), p3 = __expf(vals[kr*4+3]-mx);
      ps += (p0+p1)+(p2+p3);
      unsigned u0 = (unsigned)f2bf(p0) | ((unsigned)f2bf(p1)<<16);
      unsigned u1 = (unsigned)f2bf(p2) | ((unsigned)f2bf(p3)<<16);
      *(unsigned*)&Pl[wid][r16][kr*16 + 4*kq]     = u0;
      *(unsigned*)&Pl[wid][r16][kr*16 + 4*kq + 2] = u1;
    }
    ps += __shfl_xor(ps, 16, 64);
    ps += __shfl_xor(ps, 32, 64);
    l_r = l_r*alpha + ps; m_r = mx;
    #pragma unroll
    for(int t=0;t<4;t++)
      #pragma unroll
      for(int j=0;j<4;j++) acc[t][j] *= alpha;

    // PV: O^T[d][q] += V^T(16d x 32k) . P^T(32k x 16q), 4 d-tiles x 2 k-halves
    union { bf16x8 v8; uint2 u2[2]; } pf, vf;
    __builtin_amdgcn_s_setprio(1);
    #pragma unroll
    for(int ks2=0; ks2<2; ks2++){
      pf.u2[0] = *(const uint2*)&Pl[wid][r16][ks2*32 + kq*8];
      pf.u2[1] = *(const uint2*)&Pl[wid][r16][ks2*32 + kq*8 + 4];
      #pragma unroll
      for(int db=0; db<4; db++){
        vf.u2[0] = *(const uint2*)&VT[16*db + r16][ks2*32 + kq*8];
        vf.u2[1] = *(const uint2*)&VT[16*db + r16][ks2*32 + kq*8 + 4];
        acc[db] = __builtin_amdgcn_mfma_f32_16x16x32_bf16(vf.v8, pf.v8, acc[db], 0,0,0);
      }
    }
    __builtin_amdgcn_s_setprio(0);
  }

  // epilogue: normalize, transpose via LDS, coalesced bf16 store
  float linv = 1.f / l_r;
  #pragma unroll
  for(int db=0; db<4; db++)
    #pragma unroll
    for(int i=0;i<4;i++)
      Ol[wid][r16][16*db + 4*kq + i] = (short)f2bf(acc[db][i]*linv);
  int q = lane >> 2, c0 = (lane & 3)*16;
  const short* src = &Ol[wid][q][c0];
  uint2 a0 = *(const uint2*)(src+0), a1 = *(const uint2*)(src+4);
  uint2 a2 = *(const uint2*)(src+8), a3 = *(const uint2*)(src+12);
  ushort_t* dst = y + (size_t)(b*T_ + qw0 + q)*C_ + h*64 + c0;
  uint4 w0 = {a0.x, a0.y, a1.x, a1.y}, w1 = {a2.x, a2.y, a3.x, a3.y};
  *(uint4*)(dst+0) = w0;
  *(uint4*)(dst+8) = w1;
}

// ---------------- f32 GEMM fallback (head only, if ws too small) ----------------
__global__ __launch_bounds__(256) void gemm_nt(const float* __restrict__ A, const float* __restrict__ W,
    const float* __restrict__ bias, const float* resid, float* Cm,
    int M, int N, int K, int act){
  __shared__ float As[16][68];
  __shared__ float Bs[16][68];
  int m0 = blockIdx.y*64, n0 = blockIdx.x*64;
  int tid = threadIdx.x;
  int tx = tid & 15, ty = tid >> 4;
  float acc[4][4] = {};
  for(int k0=0;k0<K;k0+=16){
    #pragma unroll
    for(int l=0;l<4;l++){
      int li = tid + l*256;
      int r = li >> 4, c = li & 15;
      int gm = m0 + r, gn = n0 + r, gk = k0 + c;
      As[c][r] = (gm<M) ? A[(size_t)gm*K + gk] : 0.f;
      Bs[c][r] = (gn<N) ? W[(size_t)gn*K + gk] : 0.f;
    }
    __syncthreads();
    #pragma unroll
    for(int k=0;k<16;k++){
      float4 av = *(const float4*)&As[k][ty*4];
      float4 bv = *(const float4*)&Bs[k][tx*4];
      float a[4] = {av.x, av.y, av.z, av.w};
      float b4[4] = {bv.x, bv.y, bv.z, bv.w};
      #pragma unroll
      for(int i=0;i<4;i++)
        #pragma unroll
        for(int j=0;j<4;j++)
          acc[i][j] = fmaf(a[i], b4[j], acc[i][j]);
    }
    __syncthreads();
  }
  #pragma unroll
  for(int i=0;i<4;i++){
    int m = m0 + ty*4 + i; if(m>=M) continue;
    #pragma unroll
    for(int j=0;j<4;j++){
      int n = n0 + tx*4 + j; if(n>=N) continue;
      float v = acc[i][j];
      if(bias) v += bias[n];
      if(act)  v = 0.5f*v*(1.f + erff(v*0.70710678118654752f));
      if(resid) v += resid[(size_t)m*N + n];
      Cm[(size_t)m*N + n] = v;
    }
  }
}

extern "C" void kernel_launch(void* const* d_in, const int* in_sizes, int n_in,
                              void* d_out, int out_size, void* d_ws, size_t ws_size,
                              hipStream_t stream) {
  const int*   idx  = (const int*)  d_in[0];
  const float* tok  = (const float*)d_in[1];
  const float* pos  = (const float*)d_in[2];
  const float* Wq   = (const float*)d_in[3];
  const float* bq   = (const float*)d_in[4];
  const float* Wk   = (const float*)d_in[5];
  const float* bk   = (const float*)d_in[6];
  const float* Wv   = (const float*)d_in[7];
  const float* bv   = (const float*)d_in[8];
  const float* Wp   = (const float*)d_in[9];
  const float* bp   = (const float*)d_in[10];
  const float* ln1w = (const float*)d_in[11];
  const float* ln1b = (const float*)d_in[12];
  const float* ln2w = (const float*)d_in[13];
  const float* ln2b = (const float*)d_in[14];
  const float* W1   = (const float*)d_in[15];
  const float* b1   = (const float*)d_in[16];
  const float* W2   = (const float*)d_in[17];
  const float* b2   = (const float*)d_in[18];
  const float* lnfw = (const float*)d_in[19];
  const float* lnfb = (const float*)d_in[20];
  const float* headw= (const float*)d_in[21];

  float* out = (float*)d_out;
  ushort_t* qkvb = (ushort_t*)(out);                  //  6,291,456 bf16
  ushort_t* hb   = (ushort_t*)(out + 3145728);        //  2,097,152 bf16
  ushort_t* yb   = (ushort_t*)(out + 4194304);        //  2,097,152 bf16
  ushort_t* mb   = (ushort_t*)(out + 5242880);        //  8,388,608 bf16
  ushort_t* wqkv = (ushort_t*)(out + 9437184);        // 25,165,824 bf16
  ushort_t* wpb  = (ushort_t*)(out + 22020096);       //  8,388,608 bf16
  ushort_t* w1b  = (ushort_t*)(out + 26214400);       // 33,554,432 bf16
  ushort_t* w2b  = (ushort_t*)(out + 42991616);       // 33,554,432 bf16
  float*    bqkv = out + 59768832;                    //     24,576 f
  float*    x    = (float*)d_ws;
  ushort_t* xb   = (ushort_t*)((float*)d_ws + 2097152);
  ushort_t* whb  = (ushort_t*)((float*)d_ws + 3145728);
  const bool big = ws_size >= (size_t)28877312 * 4;

  cvt_blk<<<2048,256,0,stream>>>(Wq, wqkv,          CC_/4, L_, 3*CC_/4);
  cvt_blk<<<2048,256,0,stream>>>(Wk, wqkv + CC_,    CC_/4, L_, 3*CC_/4);
  cvt_blk<<<2048,256,0,stream>>>(Wv, wqkv + 2*CC_,  CC_/4, L_, 3*CC_/4);
  cvt_blk<<<2048,256,0,stream>>>(Wp, wpb,  (long)L_*CC_/4,   1, (long)L_*CC_/4);
  cvt_blk<<<2048,256,0,stream>>>(W1, w1b,  (long)L_*CC_,     1, (long)L_*CC_);
  cvt_blk<<<2048,256,0,stream>>>(W2, w2b,  (long)L_*CC_,     1, (long)L_*CC_);
  if(big) cvt_blk<<<2048,256,0,stream>>>(headw, whb, (long)V_*C_/4, 1, (long)V_*C_/4);
  pack_qkv_bias<<<L_*QLD_/256,256,0,stream>>>(bq, bk, bv, bqkv);

  embed_kernel<<<BT_*C_/256, 256, 0, stream>>>(idx, tok, pos, x);

  for(int l=0;l<L_;l++){
    ln_kernel<<<BT_,256,0,stream>>>(x, ln1w + l*C_, ln1b + l*C_, nullptr, hb);
    gemm_mfma<128><<<dim3(BT_/128, QLD_/128),256,0,stream>>>(hb, wqkv + (size_t)l*3*CC_,
        bqkv + l*QLD_, nullptr, nullptr, qkvb, BT_, QLD_, C_, 0, 0);
    flash_kernel<<<dim3(T_/64, B_*H_),256,0,stream>>>(qkvb, yb);
    gemm_mfma<64><<<dim3(BT_/128, C_/64),256,0,stream>>>(yb, wpb + (size_t)l*CC_,
        bp + l*C_, x, x, nullptr, BT_, C_, C_, 0, 0);
    ln_kernel<<<BT_,256,0,stream>>>(x, ln2w + l*C_, ln2b + l*C_, nullptr, hb);
    gemm_mfma<128><<<dim3(BT_/128, 4*C_/128),256,0,stream>>>(hb, w1b + (size_t)l*4*CC_,
        b1 + (size_t)l*4*C_, nullptr, nullptr, mb, BT_, 4*C_, C_, 1, 0);
    gemm_mfma<64><<<dim3(BT_/128, C_/64),256,0,stream>>>(mb, w2b + (size_t)l*4*CC_,
        b2 + l*C_, x, x, nullptr, BT_, C_, 4*C_, 0, 0);
  }

  if(big){
    ln_kernel<<<BT_,256,0,stream>>>(x, lnfw, lnfb, nullptr, xb);
    gemm_mfma<128><<<dim3(BT_/128, (V_+127)/128),256,0,stream>>>(xb, whb,
        nullptr, nullptr, out, nullptr, BT_, V_, C_, 0, 1);
  } else {
    ln_kernel<<<BT_,256,0,stream>>>(x, lnfw, lnfb, x, nullptr);
    gemm_nt<<<dim3((V_+63)/64, BT_/64),256,0,stream>>>(x, headw, nullptr, nullptr, out,
                                                       BT_, V_, C_, 0);
  }
}

// Round 6
// 2867.010 us; speedup vs baseline: 1.0746x; 1.0010x over previous
//
#include <hip/hip_runtime.h>
#include <math.h>

// GPT-2-ish forward: V=50257, C=1024, H=16, L=8, B=2, T=1024, D=64
#define V_ 50257
#define C_ 1024
#define H_ 16
#define L_ 8
#define B_ 2
#define T_ 1024
#define BT_ 2048
#define CC_ (C_*C_)
#define QLD_ 3072   // packed q|k|v row stride (bf16)

typedef unsigned short ushort_t;
using bf16x8 = __attribute__((ext_vector_type(8))) short;
using f32x4  = __attribute__((ext_vector_type(4))) float;

#define AS1 __attribute__((address_space(1)))
#define AS3 __attribute__((address_space(3)))
#define VMCNT6() asm volatile("s_waitcnt vmcnt(6)" ::: "memory")
#define VMCNT0() asm volatile("s_waitcnt vmcnt(0)" ::: "memory")
#define RBAR()   asm volatile("s_barrier" ::: "memory")

__device__ __forceinline__ ushort_t f2bf(float f){
  union { float f; unsigned u; } a; a.f = f;
  unsigned r = a.u + 0x7fffu + ((a.u >> 16) & 1u);   // RNE
  return (ushort_t)(r >> 16);
}

__device__ __forceinline__ float wave_sum(float v){
  #pragma unroll
  for(int o=32;o>0;o>>=1) v += __shfl_down(v,o,64);
  return v;
}

// ---------------- conversions ----------------
__global__ __launch_bounds__(256) void cvt_blk(const float* __restrict__ s, ushort_t* __restrict__ d,
    long inner4, int nblk, long dstStride4){
  long total = inner4 * nblk;
  for(long i = (long)blockIdx.x*256 + threadIdx.x; i < total; i += (long)gridDim.x*256){
    long blk = i / inner4, r = i - blk*inner4;
    float4 v = ((const float4*)s)[i];
    ushort4 o; o.x=f2bf(v.x); o.y=f2bf(v.y); o.z=f2bf(v.z); o.w=f2bf(v.w);
    ((ushort4*)d)[blk*dstStride4 + r] = o;
  }
}

__global__ __launch_bounds__(256) void pack_qkv_bias(const float* __restrict__ bq,
    const float* __restrict__ bk, const float* __restrict__ bv, float* __restrict__ dst){
  int i = blockIdx.x*256 + threadIdx.x;          // L*3072
  int l = i / QLD_, c = i - l*QLD_;
  float v;
  if(c < C_)            v = bq[l*C_ + c];
  else if(c < 2*C_)     v = bk[l*C_ + c - C_];
  else                  v = bv[l*C_ + c - 2*C_];
  dst[i] = v;
}

__global__ __launch_bounds__(256) void embed_kernel(const int* __restrict__ idx,
    const float* __restrict__ tok, const float* __restrict__ pos, float* __restrict__ x){
  int i = blockIdx.x*256 + threadIdx.x;
  int c = i & (C_-1); int bt = i >> 10; int t = bt & (T_-1);
  x[i] = tok[(size_t)idx[bt]*C_ + c] + pos[t*C_ + c];
}

// LayerNorm over C=1024; writes f32 (outF) or bf16 (outB). in==outF safe.
__global__ __launch_bounds__(256) void ln_kernel(const float* in, const float* __restrict__ w,
    const float* __restrict__ b, float* outF, ushort_t* outB){
  int row = blockIdx.x;
  const float* xr = in + (size_t)row*C_;
  float vals[4]; float sum=0.f, sq=0.f;
  #pragma unroll
  for(int l=0;l<4;l++){ float v = xr[threadIdx.x + l*256]; vals[l]=v; sum+=v; sq+=v*v; }
  __shared__ float r1[4], r2[4];
  float s1 = wave_sum(sum), s2 = wave_sum(sq);
  int wid = threadIdx.x>>6, lane = threadIdx.x&63;
  if(lane==0){ r1[wid]=s1; r2[wid]=s2; }
  __syncthreads();
  float tot  = r1[0]+r1[1]+r1[2]+r1[3];
  float tot2 = r2[0]+r2[1]+r2[2]+r2[3];
  float mu  = tot * (1.f/C_);
  float var = tot2 * (1.f/C_) - mu*mu;
  float inv = rsqrtf(var + 1e-5f);
  #pragma unroll
  for(int l=0;l<4;l++){
    int c = threadIdx.x + l*256;
    float v = (vals[l]-mu)*inv*w[c] + b[c];
    if(outB) outB[(size_t)row*C_ + c] = f2bf(v);
    else     outF[(size_t)row*C_ + c] = v;
  }
}

// ---------------- 2-phase bf16 MFMA GEMM (layer GEMMs) ----------------
template<int BN>
__global__ __launch_bounds__(256) void gemm_mfma(
    const ushort_t* __restrict__ A, const ushort_t* __restrict__ W,
    const float* __restrict__ bias, const float* resid,
    float* outF, ushort_t* outB,
    int M, int N, int K, int act, int nt)
{
  constexpr int BM = 128;
  constexpr int NSB = BN/16;          // B-subtiles (4 or 8)
  constexpr int NBF = BN/32;          // B frags per wave (2 or 4)
  __shared__ __align__(16) short sA[2][8*512];
  __shared__ __align__(16) short sB[2][NSB*512];
  const int tid  = threadIdx.x;
  const int lane = tid & 63, wid = tid >> 6;
  const int wr = wid >> 1, wc = wid & 1;
  const int nwg = gridDim.x * gridDim.y;
  const int lid = blockIdx.x + gridDim.x * blockIdx.y;
  const int swz = (lid & 7) * (nwg >> 3) + (lid >> 3);
  const int m0 = (swz % gridDim.x) * BM, n0 = (swz / gridDim.x) * BN;
  const int r16 = lane & 15, kq = lane >> 4;

  auto stage = [&](int buf, int k0){
    #pragma unroll
    for(int s2=0; s2<2; ++s2){
      int s = wid*2 + s2;
      const ushort_t* g = A + (size_t)(m0 + s*16 + r16)*K + k0 + kq*8;
      __builtin_amdgcn_global_load_lds((const AS1 void*)g,
          (AS3 void*)&sA[buf][s*512], 16, 0, 0);
    }
    #pragma unroll
    for(int s2=0; s2<NSB/4; ++s2){
      int s = wid*(NSB/4) + s2;
      int gn = n0 + s*16 + r16; if(gn >= N) gn = N-1;
      const ushort_t* g = W + (size_t)gn*K + k0 + kq*8;
      __builtin_amdgcn_global_load_lds((const AS1 void*)g,
          (AS3 void*)&sB[buf][s*512], 16, 0, 0);
    }
  };

  f32x4 acc[4][NBF];
  #pragma unroll
  for(int i=0;i<4;i++)
    #pragma unroll
    for(int j=0;j<NBF;j++) acc[i][j] = (f32x4){0.f,0.f,0.f,0.f};

  const int NT = K >> 5;
  stage(0, 0);
  int cur = 0;
  for(int t=0; t<NT; ++t){
    __syncthreads();
    if(t+1 < NT) stage(cur^1, (t+1)*32);
    bf16x8 af[4], bfr[NBF];
    #pragma unroll
    for(int m=0;m<4;m++) af[m] = *(const bf16x8*)&sA[cur][(wr*4+m)*512 + lane*8];
    #pragma unroll
    for(int n=0;n<NBF;n++) bfr[n] = *(const bf16x8*)&sB[cur][(wc*NBF+n)*512 + lane*8];
    #pragma unroll
    for(int m=0;m<4;m++)
      #pragma unroll
      for(int n=0;n<NBF;n++)
        acc[m][n] = __builtin_amdgcn_mfma_f32_16x16x32_bf16(af[m], bfr[n], acc[m][n], 0, 0, 0);
    cur ^= 1;
  }

  const int colb = n0 + wc*(BN/2);
  #pragma unroll
  for(int m=0;m<4;m++){
    int rowb = m0 + wr*64 + m*16 + kq*4;
    #pragma unroll
    for(int n=0;n<NBF;n++){
      int col = colb + n*16 + r16;
      if(col >= N) continue;
      float bv = bias ? bias[col] : 0.f;
      #pragma unroll
      for(int i=0;i<4;i++){
        int row = rowb + i;
        float v = acc[m][n][i] + bv;
        if(act) v = 0.5f*v*(1.f + erff(v*0.70710678118654752f));
        if(resid) v += resid[(size_t)row*N + col];
        if(outB) outB[(size_t)row*N + col] = f2bf(v);
        else if(nt) __builtin_nontemporal_store(v, &outF[(size_t)row*N + col]);
        else outF[(size_t)row*N + col] = v;
      }
    }
  }
}

// ---------------- 8-phase 256x256 bf16 MFMA GEMM (head) ----------------
// BK=64, 512 thr = 8 waves (2M x 4N), per-wave out 128x64, 16 MFMA/phase,
// raw barriers + counted vmcnt (loads stay in flight across barriers).
// Derived schedule: quadrants (mh,nh) = (0,0),(0,1),(1,1),(1,0);
// stages: j0: T+1.A1 | j1: T+2.A0 | j2: T+2.B0 | j3: T+2.B1 + vmcnt(6).
// Per-wave loads/half = 2 -> vmcnt(6) = 3 half-tiles in flight.
// f32 nontemporal output. Requires M%256==0, K%64==0, NT>=2, nwg%8==0.
__global__ __launch_bounds__(512) void gemm_8ph(
    const ushort_t* __restrict__ A, const ushort_t* __restrict__ W,
    float* __restrict__ outF, int M, int N, int K, int gx)
{
  __shared__ __align__(16) short sA[2][2][8192];   // [buf][half][sub*1024+ks*512+lane*8]
  __shared__ __align__(16) short sB[2][2][8192];
  const int tid = threadIdx.x, lane = tid & 63;
  const int wid = tid >> 6, wm = wid & 1, wn = wid >> 1;   // 2M x 4N
  const int r16 = lane & 15, kq = lane >> 4;
  const int nwg = gridDim.x;
  const int L = blockIdx.x;
  const int swz = (L & 7) * (nwg >> 3) + (L >> 3);
  const int m0 = (swz % gx) * 256, n0 = (swz / gx) * 256;

  // stage one 16KB half (128 rows x 64 k) of A or B: 2 x global_load_lds/thread
  auto stage = [&](int buf, int half, int isB, int k0){
    const ushort_t* base = isB ? W : A;
    const int off0 = (isB ? n0 : m0) + half*128;
    short* dst0 = isB ? &sB[buf][half][0] : &sA[buf][half][0];
    #pragma unroll
    for(int i=0;i<2;i++){
      int sub = i*4 + (tid>>7);
      int rem = tid & 127;
      int row = off0 + sub*16 + (rem & 15);
      if(isB && row >= N) row = N-1;
      int kk = k0 + ((rem>>6)&1)*32 + ((rem>>4)&3)*8;
      __builtin_amdgcn_global_load_lds((const AS1 void*)(base + (size_t)row*K + kk),
          (AS3 void*)(dst0 + i*4096 + tid*8), 16, 0, 0);
    }
  };

  f32x4 acc[2][2][4][2];
  #pragma unroll
  for(int a=0;a<2;a++)
    #pragma unroll
    for(int b=0;b<2;b++)
      #pragma unroll
      for(int m=0;m<4;m++)
        #pragma unroll
        for(int n=0;n<2;n++) acc[a][b][m][n] = (f32x4){0.f,0.f,0.f,0.f};

  const int NT = K >> 6;
  // prologue: T0.A0, T0.B0, T0.B1, T0.A1, T1.A0, T1.B0, T1.B1
  stage(0,0,0, 0); stage(0,0,1, 0); stage(0,1,1, 0); stage(0,1,0, 0);
  if(NT>1){ stage(1,0,0, 64); stage(1,0,1, 64); stage(1,1,1, 64); }
  VMCNT6();
  RBAR();

  bf16x8 af[4][2], bfr[2][2][2];   // af[m][ks]; bfr[nh][n][ks]

  for(int t=0; t<NT; ++t){
    const int buf = t & 1;
    const int k1 = (t+1)<<6, k2 = (t+2)<<6;
    const bool s1 = (t+1) < NT, s2 = (t+2) < NT;

    // ---- j0: quadrant (0,0) ----
    if(s1) stage(buf^1, 1, 0, k1);            // T+1.A1
    #pragma unroll
    for(int m=0;m<4;m++)
      #pragma unroll
      for(int ks=0;ks<2;ks++)
        af[m][ks] = *(const bf16x8*)&sA[buf][0][(wm*4+m)*1024 + ks*512 + lane*8];
    #pragma unroll
    for(int n=0;n<2;n++)
      #pragma unroll
      for(int ks=0;ks<2;ks++)
        bfr[0][n][ks] = *(const bf16x8*)&sB[buf][0][(wn*2+n)*1024 + ks*512 + lane*8];
    RBAR();
    __builtin_amdgcn_s_setprio(1);
    #pragma unroll
    for(int m=0;m<4;m++)
      #pragma unroll
      for(int n=0;n<2;n++)
        #pragma unroll
        for(int ks=0;ks<2;ks++)
          acc[0][0][m][n] = __builtin_amdgcn_mfma_f32_16x16x32_bf16(af[m][ks], bfr[0][n][ks], acc[0][0][m][n], 0,0,0);
    __builtin_amdgcn_s_setprio(0);
    RBAR();

    // ---- j1: quadrant (0,1) ----
    if(s2) stage(buf, 0, 0, k2);              // T+2.A0
    #pragma unroll
    for(int n=0;n<2;n++)
      #pragma unroll
      for(int ks=0;ks<2;ks++)
        bfr[1][n][ks] = *(const bf16x8*)&sB[buf][1][(wn*2+n)*1024 + ks*512 + lane*8];
    RBAR();
    __builtin_amdgcn_s_setprio(1);
    #pragma unroll
    for(int m=0;m<4;m++)
      #pragma unroll
      for(int n=0;n<2;n++)
        #pragma unroll
        for(int ks=0;ks<2;ks++)
          acc[0][1][m][n] = __builtin_amdgcn_mfma_f32_16x16x32_bf16(af[m][ks], bfr[1][n][ks], acc[0][1][m][n], 0,0,0);
    __builtin_amdgcn_s_setprio(0);
    RBAR();

    // ---- j2: quadrant (1,1) ----
    if(s2) stage(buf, 0, 1, k2);              // T+2.B0
    #pragma unroll
    for(int m=0;m<4;m++)
      #pragma unroll
      for(int ks=0;ks<2;ks++)
        af[m][ks] = *(const bf16x8*)&sA[buf][1][(wm*4+m)*1024 + ks*512 + lane*8];
    RBAR();
    __builtin_amdgcn_s_setprio(1);
    #pragma unroll
    for(int m=0;m<4;m++)
      #pragma unroll
      for(int n=0;n<2;n++)
        #pragma unroll
        for(int ks=0;ks<2;ks++)
          acc[1][1][m][n] = __builtin_amdgcn_mfma_f32_16x16x32_bf16(af[m][ks], bfr[1][n][ks], acc[1][1][m][n], 0,0,0);
    __builtin_amdgcn_s_setprio(0);
    RBAR();

    // ---- j3: quadrant (1,0) ----
    if(s2) stage(buf, 1, 1, k2);              // T+2.B1
    if(s2) { VMCNT6(); } else { VMCNT0(); }
    RBAR();
    __builtin_amdgcn_s_setprio(1);
    #pragma unroll
    for(int m=0;m<4;m++)
      #pragma unroll
      for(int n=0;n<2;n++)
        #pragma unroll
        for(int ks=0;ks<2;ks++)
          acc[1][0][m][n] = __builtin_amdgcn_mfma_f32_16x16x32_bf16(af[m][ks], bfr[0][n][ks], acc[1][0][m][n], 0,0,0);
    __builtin_amdgcn_s_setprio(0);
    RBAR();
  }

  // epilogue: f32 nontemporal stores
  #pragma unroll
  for(int mh=0;mh<2;mh++)
    #pragma unroll
    for(int nh=0;nh<2;nh++)
      #pragma unroll
      for(int m=0;m<4;m++){
        int rowb = m0 + mh*128 + wm*64 + m*16 + kq*4;
        #pragma unroll
        for(int n=0;n<2;n++){
          int col = n0 + nh*128 + wn*32 + n*16 + r16;
          if(col >= N) continue;
          #pragma unroll
          for(int i=0;i<4;i++)
            __builtin_nontemporal_store(acc[mh][nh][m][n][i], &outF[(size_t)(rowb+i)*N + col]);
        }
      }
}

// ---------------- fused flash attention (bf16 MFMA, KVBLK=64) ----------------
__global__ __launch_bounds__(256) void flash_kernel(const ushort_t* __restrict__ qkv,
    ushort_t* __restrict__ y){
  const int tid = threadIdx.x, lane = tid & 63, wid = tid >> 6;
  const int r16 = lane & 15, kq = lane >> 4;
  const int lid = blockIdx.x + 16*blockIdx.y;
  const int swz = (lid & 7)*64 + (lid >> 3);
  const int qt = swz & 15, bh = swz >> 4;
  const int b = bh >> 4, h = bh & 15;
  const int q0 = qt*64, qw0 = q0 + wid*16;
  const int qa = qw0 + r16;

  __shared__ __align__(16) short Kt[8][512];
  __shared__ __align__(16) short VT[64][68];
  __shared__ __align__(16) short Pl[4][16][68];
  __shared__ __align__(16) short Ol[4][16][68];

  const size_t rowQ = (size_t)(b*T_ + qa)*QLD_ + h*64 + kq*8;
  bf16x8 qf0 = *(const bf16x8*)(qkv + rowQ);
  bf16x8 qf1 = *(const bf16x8*)(qkv + rowQ + 32);

  f32x4 acc[4];
  #pragma unroll
  for(int t=0;t<4;t++) acc[t] = (f32x4){0.f,0.f,0.f,0.f};
  float m_r = -INFINITY, l_r = 0.f;

  const int njt = qt + 1;
  for(int jt=0; jt<njt; ++jt){
    __syncthreads();
    #pragma unroll
    for(int s2=0;s2<2;s2++){
      int s = wid*2 + s2;
      const ushort_t* g = qkv + (size_t)(b*T_ + jt*64 + (s>>1)*16 + r16)*QLD_
                          + C_ + h*64 + (s&1)*32 + kq*8;
      __builtin_amdgcn_global_load_lds((const AS1 void*)g,
          (AS3 void*)&Kt[s][lane*8], 16, 0, 0);
    }
    #pragma unroll
    for(int a2=0;a2<2;a2++){
      int d0 = (a2*4 + wid)*8;
      bf16x8 vv = *(const bf16x8*)(qkv + (size_t)(b*T_ + jt*64 + lane)*QLD_ + 2*C_ + h*64 + d0);
      #pragma unroll
      for(int j=0;j<8;j++) VT[d0+j][lane] = vv[j];
    }
    __syncthreads();

    f32x4 st[4];
    __builtin_amdgcn_s_setprio(1);
    #pragma unroll
    for(int kr=0;kr<4;kr++){
      st[kr] = (f32x4){0.f,0.f,0.f,0.f};
      st[kr] = __builtin_amdgcn_mfma_f32_16x16x32_bf16(*(const bf16x8*)&Kt[kr*2+0][lane*8], qf0, st[kr], 0,0,0);
      st[kr] = __builtin_amdgcn_mfma_f32_16x16x32_bf16(*(const bf16x8*)&Kt[kr*2+1][lane*8], qf1, st[kr], 0,0,0);
    }
    __builtin_amdgcn_s_setprio(0);

    float vals[16]; float mx = m_r;
    if(jt == njt-1){
      #pragma unroll
      for(int kr=0;kr<4;kr++)
        #pragma unroll
        for(int i=0;i<4;i++){
          int ka = jt*64 + kr*16 + 4*kq + i;
          float v = (ka <= qa) ? st[kr][i]*0.125f : -INFINITY;
          vals[kr*4+i] = v; mx = fmaxf(mx, v);
        }
    } else {
      #pragma unroll
      for(int kr=0;kr<4;kr++)
        #pragma unroll
        for(int i=0;i<4;i++){
          float v = st[kr][i]*0.125f;
          vals[kr*4+i] = v; mx = fmaxf(mx, v);
        }
    }
    mx = fmaxf(mx, __shfl_xor(mx, 16, 64));
    mx = fmaxf(mx, __shfl_xor(mx, 32, 64));
    float alpha = __expf(m_r - mx);
    float ps = 0.f;
    #pragma unroll
    for(int kr=0;kr<4;kr++){
      float p0 = __expf(vals[kr*4+0]-mx), p1 = __expf(vals[kr*4+1]-mx);
      float p2 = __expf(vals[kr*4+2]-mx), p3 = __expf(vals[kr*4+3]-mx);
      ps += (p0+p1)+(p2+p3);
      unsigned u0 = (unsigned)f2bf(p0) | ((unsigned)f2bf(p1)<<16);
      unsigned u1 = (unsigned)f2bf(p2) | ((unsigned)f2bf(p3)<<16);
      *(unsigned*)&Pl[wid][r16][kr*16 + 4*kq]     = u0;
      *(unsigned*)&Pl[wid][r16][kr*16 + 4*kq + 2] = u1;
    }
    ps += __shfl_xor(ps, 16, 64);
    ps += __shfl_xor(ps, 32, 64);
    l_r = l_r*alpha + ps; m_r = mx;
    #pragma unroll
    for(int t=0;t<4;t++)
      #pragma unroll
      for(int j=0;j<4;j++) acc[t][j] *= alpha;

    union { bf16x8 v8; uint2 u2[2]; } pf, vf;
    __builtin_amdgcn_s_setprio(1);
    #pragma unroll
    for(int ks2=0; ks2<2; ks2++){
      pf.u2[0] = *(const uint2*)&Pl[wid][r16][ks2*32 + kq*8];
      pf.u2[1] = *(const uint2*)&Pl[wid][r16][ks2*32 + kq*8 + 4];
      #pragma unroll
      for(int db=0; db<4; db++){
        vf.u2[0] = *(const uint2*)&VT[16*db + r16][ks2*32 + kq*8];
        vf.u2[1] = *(const uint2*)&VT[16*db + r16][ks2*32 + kq*8 + 4];
        acc[db] = __builtin_amdgcn_mfma_f32_16x16x32_bf16(vf.v8, pf.v8, acc[db], 0,0,0);
      }
    }
    __builtin_amdgcn_s_setprio(0);
  }

  float linv = 1.f / l_r;
  #pragma unroll
  for(int db=0; db<4; db++)
    #pragma unroll
    for(int i=0;i<4;i++)
      Ol[wid][r16][16*db + 4*kq + i] = (short)f2bf(acc[db][i]*linv);
  int q = lane >> 2, c0 = (lane & 3)*16;
  const short* src = &Ol[wid][q][c0];
  uint2 a0 = *(const uint2*)(src+0), a1 = *(const uint2*)(src+4);
  uint2 a2 = *(const uint2*)(src+8), a3 = *(const uint2*)(src+12);
  ushort_t* dst = y + (size_t)(b*T_ + qw0 + q)*C_ + h*64 + c0;
  uint4 w0 = {a0.x, a0.y, a1.x, a1.y}, w1 = {a2.x, a2.y, a3.x, a3.y};
  *(uint4*)(dst+0) = w0;
  *(uint4*)(dst+8) = w1;
}

// ---------------- f32 GEMM fallback (head only, if ws too small) ----------------
__global__ __launch_bounds__(256) void gemm_nt(const float* __restrict__ A, const float* __restrict__ W,
    const float* __restrict__ bias, const float* resid, float* Cm,
    int M, int N, int K, int act){
  __shared__ float As[16][68];
  __shared__ float Bs[16][68];
  int m0 = blockIdx.y*64, n0 = blockIdx.x*64;
  int tid = threadIdx.x;
  int tx = tid & 15, ty = tid >> 4;
  float acc[4][4] = {};
  for(int k0=0;k0<K;k0+=16){
    #pragma unroll
    for(int l=0;l<4;l++){
      int li = tid + l*256;
      int r = li >> 4, c = li & 15;
      int gm = m0 + r, gn = n0 + r, gk = k0 + c;
      As[c][r] = (gm<M) ? A[(size_t)gm*K + gk] : 0.f;
      Bs[c][r] = (gn<N) ? W[(size_t)gn*K + gk] : 0.f;
    }
    __syncthreads();
    #pragma unroll
    for(int k=0;k<16;k++){
      float4 av = *(const float4*)&As[k][ty*4];
      float4 bv = *(const float4*)&Bs[k][tx*4];
      float a[4] = {av.x, av.y, av.z, av.w};
      float b4[4] = {bv.x, bv.y, bv.z, bv.w};
      #pragma unroll
      for(int i=0;i<4;i++)
        #pragma unroll
        for(int j=0;j<4;j++)
          acc[i][j] = fmaf(a[i], b4[j], acc[i][j]);
    }
    __syncthreads();
  }
  #pragma unroll
  for(int i=0;i<4;i++){
    int m = m0 + ty*4 + i; if(m>=M) continue;
    #pragma unroll
    for(int j=0;j<4;j++){
      int n = n0 + tx*4 + j; if(n>=N) continue;
      float v = acc[i][j];
      if(bias) v += bias[n];
      if(act)  v = 0.5f*v*(1.f + erff(v*0.70710678118654752f));
      if(resid) v += resid[(size_t)m*N + n];
      Cm[(size_t)m*N + n] = v;
    }
  }
}

extern "C" void kernel_launch(void* const* d_in, const int* in_sizes, int n_in,
                              void* d_out, int out_size, void* d_ws, size_t ws_size,
                              hipStream_t stream) {
  const int*   idx  = (const int*)  d_in[0];
  const float* tok  = (const float*)d_in[1];
  const float* pos  = (const float*)d_in[2];
  const float* Wq   = (const float*)d_in[3];
  const float* bq   = (const float*)d_in[4];
  const float* Wk   = (const float*)d_in[5];
  const float* bk   = (const float*)d_in[6];
  const float* Wv   = (const float*)d_in[7];
  const float* bv   = (const float*)d_in[8];
  const float* Wp   = (const float*)d_in[9];
  const float* bp   = (const float*)d_in[10];
  const float* ln1w = (const float*)d_in[11];
  const float* ln1b = (const float*)d_in[12];
  const float* ln2w = (const float*)d_in[13];
  const float* ln2b = (const float*)d_in[14];
  const float* W1   = (const float*)d_in[15];
  const float* b1   = (const float*)d_in[16];
  const float* W2   = (const float*)d_in[17];
  const float* b2   = (const float*)d_in[18];
  const float* lnfw = (const float*)d_in[19];
  const float* lnfb = (const float*)d_in[20];
  const float* headw= (const float*)d_in[21];

  float* out = (float*)d_out;
  ushort_t* qkvb = (ushort_t*)(out);                  //  6,291,456 bf16
  ushort_t* hb   = (ushort_t*)(out + 3145728);        //  2,097,152 bf16
  ushort_t* yb   = (ushort_t*)(out + 4194304);        //  2,097,152 bf16
  ushort_t* mb   = (ushort_t*)(out + 5242880);        //  8,388,608 bf16
  ushort_t* wqkv = (ushort_t*)(out + 9437184);        // 25,165,824 bf16
  ushort_t* wpb  = (ushort_t*)(out + 22020096);       //  8,388,608 bf16
  ushort_t* w1b  = (ushort_t*)(out + 26214400);       // 33,554,432 bf16
  ushort_t* w2b  = (ushort_t*)(out + 42991616);       // 33,554,432 bf16
  float*    bqkv = out + 59768832;                    //     24,576 f
  float*    x    = (float*)d_ws;
  ushort_t* xb   = (ushort_t*)((float*)d_ws + 2097152);
  ushort_t* whb  = (ushort_t*)((float*)d_ws + 3145728);
  const bool big = ws_size >= (size_t)28877312 * 4;

  cvt_blk<<<2048,256,0,stream>>>(Wq, wqkv,          CC_/4, L_, 3*CC_/4);
  cvt_blk<<<2048,256,0,stream>>>(Wk, wqkv + CC_,    CC_/4, L_, 3*CC_/4);
  cvt_blk<<<2048,256,0,stream>>>(Wv, wqkv + 2*CC_,  CC_/4, L_, 3*CC_/4);
  cvt_blk<<<2048,256,0,stream>>>(Wp, wpb,  (long)L_*CC_/4,   1, (long)L_*CC_/4);
  cvt_blk<<<2048,256,0,stream>>>(W1, w1b,  (long)L_*CC_,     1, (long)L_*CC_);
  cvt_blk<<<2048,256,0,stream>>>(W2, w2b,  (long)L_*CC_,     1, (long)L_*CC_);
  if(big) cvt_blk<<<2048,256,0,stream>>>(headw, whb, (long)V_*C_/4, 1, (long)V_*C_/4);
  pack_qkv_bias<<<L_*QLD_/256,256,0,stream>>>(bq, bk, bv, bqkv);

  embed_kernel<<<BT_*C_/256, 256, 0, stream>>>(idx, tok, pos, x);

  for(int l=0;l<L_;l++){
    ln_kernel<<<BT_,256,0,stream>>>(x, ln1w + l*C_, ln1b + l*C_, nullptr, hb);
    gemm_mfma<128><<<dim3(BT_/128, QLD_/128),256,0,stream>>>(hb, wqkv + (size_t)l*3*CC_,
        bqkv + l*QLD_, nullptr, nullptr, qkvb, BT_, QLD_, C_, 0, 0);
    flash_kernel<<<dim3(T_/64, B_*H_),256,0,stream>>>(qkvb, yb);
    gemm_mfma<64><<<dim3(BT_/128, C_/64),256,0,stream>>>(yb, wpb + (size_t)l*CC_,
        bp + l*C_, x, x, nullptr, BT_, C_, C_, 0, 0);
    ln_kernel<<<BT_,256,0,stream>>>(x, ln2w + l*C_, ln2b + l*C_, nullptr, hb);
    gemm_mfma<128><<<dim3(BT_/128, 4*C_/128),256,0,stream>>>(hb, w1b + (size_t)l*4*CC_,
        b1 + (size_t)l*4*C_, nullptr, nullptr, mb, BT_, 4*C_, C_, 1, 0);
    gemm_mfma<64><<<dim3(BT_/128, C_/64),256,0,stream>>>(mb, w2b + (size_t)l*4*CC_,
        b2 + l*C_, x, x, nullptr, BT_, C_, 4*C_, 0, 0);
  }

  if(big){
    ln_kernel<<<BT_,256,0,stream>>>(x, lnfw, lnfb, nullptr, xb);
    // 8-phase head: grid = 8 x 197 = 1576 blocks (nwg % 8 == 0 -> bijective swizzle)
    gemm_8ph<<<dim3((BT_/256) * ((V_+255)/256)),512,0,stream>>>(xb, whb, out,
        BT_, V_, C_, BT_/256);
  } else {
    ln_kernel<<<BT_,256,0,stream>>>(x, lnfw, lnfb, x, nullptr);
    gemm_nt<<<dim3((V_+63)/64, BT_/64),256,0,stream>>>(x, headw, nullptr, nullptr, out,
                                                       BT_, V_, C_, 0);
  }
}